// Round 1
// baseline (112.606 us; speedup 1.0000x reference)
//
#include <hip/hip_runtime.h>

// QuantumLayer: 8-qubit, 4-layer VQC via complex 16x16 MFMA matmuls.
// State = 16x16 complex matrix (u = qubits 0-3 / index bits 7-4, l = qubits 4-7 / bits 3-0).
// Per layer: pass L: X = (P_hi * H) * M   (2 mfma_f32_16x16x32_f16, re/im K-stacked)
//            pass R: Y = L * X^T          (2 mfma)
// CNOT(3,4) + lower CNOT chain folded into LDS write addressing between passes.
// Measurement: p = |amp|^2 buffered for 16 elements, then 8 sign-matrix MFMAs.

typedef _Float16 half8  __attribute__((ext_vector_type(8)));
typedef _Float16 half2v __attribute__((ext_vector_type(2)));
typedef float    float4v __attribute__((ext_vector_type(4)));
typedef unsigned int uint2v __attribute__((ext_vector_type(2)));

#define LSTRIDE 144   // 16-aligned line stride; banks 36 mod 32 = 4 apart -> 2-way (free)
#define BUFA 0        // pass-L output (lines = u), 16*144 = 2304 B
#define BUFB 2304     // pass-R output (lines = l), 2304 B
#define PBUF 4608     // p-buffer: 16 elements * 528 B = 8448 B
#define PSTRIDE 528
#define WAVE_LDS 13056

#define MEMFENCE() __asm__ volatile("" ::: "memory")

__device__ __forceinline__ unsigned pk(float a, float b) {
  half2v v = { (_Float16)a, (_Float16)b };   // RNE conversions (avoid RTZ norm-shrink bias)
  return __builtin_bit_cast(unsigned, v);
}

// ---------------- setup: build A-fragments (gates + signs) into d_ws ----------------
// Fragment f (24 total), lane-sliced: ws_half8[f*64 + lane]. A-layout: A[m=lane&15][k=quad*8+j].
// k-interleave: k = 2*col + comp (comp 0 = re-plane coefficient, 1 = im-plane).
__global__ void qsetup(const float* __restrict__ w, _Float16* __restrict__ wsf) {
  const int lane = threadIdx.x;
  const int quad = lane >> 4, m = lane & 15;
  half8* F = (half8*)wsf;
  // pi_hi(m) = sigma0(sigma1(sigma2(m))): row perm for CNOTs 0,1,2 (folded into H rows)
  int mr = m ^ ((m >> 1) & 1);
  mr ^= ((mr >> 2) & 1) << 1;
  mr ^= ((mr >> 3) & 1) << 2;
  for (int t = 0; t < 4; ++t) {
    float gr[8][2][2], gi[8][2][2];
    for (int q = 0; q < 8; ++q) {
      float th = w[(t * 8 + q) * 2 + 0];
      float tz = w[(t * 8 + q) * 2 + 1];
      float c = cosf(0.5f * th), s = sinf(0.5f * th);
      float zc = cosf(0.5f * tz), zs = sinf(0.5f * tz);
      // g = diag(e^{-i tz/2}, e^{+i tz/2}) * RY(th)
      gr[q][0][0] =  zc * c; gi[q][0][0] = -zs * c;
      gr[q][0][1] = -zc * s; gi[q][0][1] =  zs * s;
      gr[q][1][0] =  zc * s; gi[q][1][0] =  zs * s;
      gr[q][1][1] =  zc * c; gi[q][1][1] =  zs * c;
    }
    half8 aR, aI, bR, bI;
    for (int j = 0; j < 8; ++j) {
      const int col = quad * 4 + (j >> 1), comp = j & 1;
      // H~[m][col] = H[pi_hi(m)][col], H = kron(g0,g1,g2,g3)
      float hr = 1.f, hi = 0.f;
      for (int qq = 0; qq < 4; ++qq) {
        int rb = (mr >> (3 - qq)) & 1, cb = (col >> (3 - qq)) & 1;
        float ar = gr[qq][rb][cb], ai = gi[qq][rb][cb];
        float nr = hr * ar - hi * ai, ni = hr * ai + hi * ar;
        hr = nr; hi = ni;
      }
      aR[j] = comp ? (_Float16)(-hi) : (_Float16)hr;  // A_R = [G_r, -G_i] interleaved
      aI[j] = comp ? (_Float16)(hr)  : (_Float16)hi;  // A_I = [G_i,  G_r]
      // L[m][col] = kron(g4,g5,g6,g7) (no row perm; lower CNOTs folded into write addr)
      float wr = 1.f, wi = 0.f;
      for (int qq = 4; qq < 8; ++qq) {
        int rb = (m >> (7 - qq)) & 1, cb = (col >> (7 - qq)) & 1;
        float ar = gr[qq][rb][cb], ai = gi[qq][rb][cb];
        float nr = wr * ar - wi * ai, ni = wr * ai + wi * ar;
        wr = nr; wi = ni;
      }
      bR[j] = comp ? (_Float16)(-wi) : (_Float16)wr;
      bI[j] = comp ? (_Float16)(wr)  : (_Float16)wi;
    }
    F[(t * 4 + 0) * 64 + lane] = aR;
    F[(t * 4 + 1) * 64 + lane] = aI;
    F[(t * 4 + 2) * 64 + lane] = bR;
    F[(t * 4 + 3) * 64 + lane] = bI;
  }
  // Sign fragments: A[m=qubit][k = state slot s = u*16 + l'], slot permutation absorbed:
  // true l = sigma456^{-1}(l' ^ ((u&1)<<3)); sign = 1 - 2*bit_q(true idx); rows 8-15 = 0.
  for (int c = 0; c < 8; ++c) {
    half8 sg;
    for (int j = 0; j < 8; ++j) {
      int s_ = c * 32 + quad * 8 + j;
      int u = s_ >> 4, lp = s_ & 15;
      int y = lp ^ ((u & 1) << 3);
      y ^= ((y >> 3) & 1) << 2;  // sigma4
      y ^= ((y >> 2) & 1) << 1;  // sigma5
      y ^= (y >> 1) & 1;         // sigma6
      float sv = 0.f;
      if (m < 8) {
        int bit = (m < 4) ? ((u >> (3 - m)) & 1) : ((y >> (7 - m)) & 1);
        sv = bit ? -1.f : 1.f;
      }
      sg[j] = (_Float16)sv;
    }
    F[(16 + c) * 64 + lane] = sg;
  }
}

// ---------------- main kernel: 1024 blocks * 4 waves, 16 elements per wave ----------------
__launch_bounds__(256)
__global__ void qmain(const float* __restrict__ x, const _Float16* __restrict__ wsf,
                      float* __restrict__ out) {
  __shared__ __align__(16) unsigned char smem[4 * WAVE_LDS];
  const int tid = threadIdx.x;
  const int lane = tid & 63, wv = tid >> 6;
  const int quad = lane >> 4, n = lane & 15;
  unsigned char* sm = smem + wv * WAVE_LDS;
  const half8* F = (const half8*)wsf;

  half8 aLR[4], aLI[4], aRR[4], aRI[4];
#pragma unroll
  for (int t = 0; t < 4; ++t) {
    aLR[t] = F[(t * 4 + 0) * 64 + lane];
    aLI[t] = F[(t * 4 + 1) * 64 + lane];
    aRR[t] = F[(t * 4 + 2) * 64 + lane];
    aRI[t] = F[(t * 4 + 3) * 64 + lane];
  }

  // Per-wave-constant LDS addresses (byte offsets into sm):
  const unsigned wA0 = BUFA + quad * (4 * LSTRIDE) + n * 4;  // pass-L out: line u=quad*4+r, pos l=n
  const unsigned rA  = BUFA + n * LSTRIDE + quad * 16;       // pass-R B-frag: line u=n
  const unsigned rB  = BUFB + n * LSTRIDE + quad * 16;       // pass-L B-frag: line l=n
  unsigned wB[4];                                            // pass-R out with CNOT perms folded
#pragma unroll
  for (int r = 0; r < 4; ++r) {
    int lp = quad * 4 + r;
    int y = lp ^ ((n & 1) << 3);     // C3: control = u bit0 (u = n), target = l bit3
    y ^= ((y >> 3) & 1) << 2;        // sigma456^{-1} = s6(s5(s4(.)))
    y ^= ((y >> 2) & 1) << 1;
    y ^= (y >> 1) & 1;
    wB[r] = BUFB + (unsigned)y * LSTRIDE + n * 4;
  }
  const unsigned pw = PBUF + n * 32 + quad * 8;  // p slots s = u*16 + l', u=n, l'=quad*4+r

  const int group = blockIdx.x * 4 + wv;  // 4096 groups of 16 elements
  const int e0 = group * 16;
  const float4v zz = {0.f, 0.f, 0.f, 0.f};

  for (int e = 0; e < 16; ++e) {
    // ---- encoding: product state, B-fragment for layer-0 pass L built in registers ----
    const float* xe = x + (size_t)(e0 + e) * 8;
    float xv = (lane < 8) ? xe[lane] : 0.f;
    float cc = __cosf(0.5f * xv), ss = __sinf(0.5f * xv);
    float cq[8], sq[8];
#pragma unroll
    for (int q = 0; q < 8; ++q) { cq[q] = __shfl(cc, q, 64); sq[q] = __shfl(ss, q, 64); }
    float f0 = (quad & 2) ? sq[0] : cq[0];
    float f1 = (quad & 1) ? sq[1] : cq[1];
    float f4 = (n & 8) ? sq[4] : cq[4];
    float f5 = (n & 4) ? sq[5] : cq[5];
    float f6 = (n & 2) ? sq[6] : cq[6];
    float f7 = (n & 1) ? sq[7] : cq[7];
    float pb = f0 * f1 * f4 * f5 * f6 * f7;
    float v0 = pb * cq[2] * cq[3], v1 = pb * cq[2] * sq[3];
    float v2 = pb * sq[2] * cq[3], v3 = pb * sq[2] * sq[3];
    half8 bf;
    bf[0] = (_Float16)v0; bf[1] = (_Float16)0.f;
    bf[2] = (_Float16)v1; bf[3] = (_Float16)0.f;
    bf[4] = (_Float16)v2; bf[5] = (_Float16)0.f;
    bf[6] = (_Float16)v3; bf[7] = (_Float16)0.f;

#pragma unroll
    for (int t = 0; t < 4; ++t) {
      // ---- pass L: X = H~ * M ----
      half8 bL;
      if (t == 0) { bL = bf; }
      else { MEMFENCE(); bL = *(const half8*)(sm + rB); }
      float4v xr = __builtin_amdgcn_mfma_f32_16x16x32_f16(aLR[t], bL, zz, 0, 0, 0);
      float4v xi = __builtin_amdgcn_mfma_f32_16x16x32_f16(aLI[t], bL, zz, 0, 0, 0);
      MEMFENCE();
      *(unsigned*)(sm + wA0 + 0 * LSTRIDE) = pk(xr[0], xi[0]);
      *(unsigned*)(sm + wA0 + 1 * LSTRIDE) = pk(xr[1], xi[1]);
      *(unsigned*)(sm + wA0 + 2 * LSTRIDE) = pk(xr[2], xi[2]);
      *(unsigned*)(sm + wA0 + 3 * LSTRIDE) = pk(xr[3], xi[3]);
      // ---- pass R: Y = L * X^T ----
      MEMFENCE();
      half8 bRf = *(const half8*)(sm + rA);
      float4v yr = __builtin_amdgcn_mfma_f32_16x16x32_f16(aRR[t], bRf, zz, 0, 0, 0);
      float4v yi = __builtin_amdgcn_mfma_f32_16x16x32_f16(aRI[t], bRf, zz, 0, 0, 0);
      MEMFENCE();
      if (t < 3) {
        *(unsigned*)(sm + wB[0]) = pk(yr[0], yi[0]);
        *(unsigned*)(sm + wB[1]) = pk(yr[1], yi[1]);
        *(unsigned*)(sm + wB[2]) = pk(yr[2], yi[2]);
        *(unsigned*)(sm + wB[3]) = pk(yr[3], yi[3]);
      } else {
        float p0 = yr[0] * yr[0] + yi[0] * yi[0];
        float p1 = yr[1] * yr[1] + yi[1] * yi[1];
        float p2 = yr[2] * yr[2] + yi[2] * yi[2];
        float p3 = yr[3] * yr[3] + yi[3] * yi[3];
        uint2v pv = { pk(p0, p1), pk(p2, p3) };
        *(uint2v*)(sm + pw + e * PSTRIDE) = pv;
      }
    }
  }

  // ---- measurement: exps(16 elems x 8 qubits) = Sign(16x256) * P(256x16), 8 MFMAs ----
  half8 sf[8];
#pragma unroll
  for (int c = 0; c < 8; ++c) sf[c] = F[(16 + c) * 64 + lane];
  float4v acc = {0.f, 0.f, 0.f, 0.f};
  MEMFENCE();
#pragma unroll
  for (int c = 0; c < 8; ++c) {
    half8 pbv = *(const half8*)(sm + PBUF + n * PSTRIDE + c * 64 + quad * 16);
    acc = __builtin_amdgcn_mfma_f32_16x16x32_f16(sf[c], pbv, acc, 0, 0, 0);
  }
  // C layout: col = lane&15 = element, row = quad*4+reg = qubit (rows 8-15 are zero)
  if (quad < 2) {
    float* o = out + (size_t)(e0 + n) * 8 + quad * 4;
    o[0] = acc[0]; o[1] = acc[1]; o[2] = acc[2]; o[3] = acc[3];
  }
}

extern "C" void kernel_launch(void* const* d_in, const int* in_sizes, int n_in,
                              void* d_out, int out_size, void* d_ws, size_t ws_size,
                              hipStream_t stream) {
  const float* x = (const float*)d_in[0];
  const float* w = (const float*)d_in[1];
  float* out = (float*)d_out;
  _Float16* fr = (_Float16*)d_ws;  // 24 fragments * 64 lanes * 16 B = 24576 B
  qsetup<<<dim3(1), dim3(64), 0, stream>>>(w, fr);
  qmain<<<dim3(1024), dim3(256), 0, stream>>>(x, fr, out);
}

// Round 2
// 96.497 us; speedup vs baseline: 1.1669x; 1.1669x over previous
//
#include <hip/hip_runtime.h>

// QuantumLayer: 8-qubit, 4-layer VQC via complex 16x16 MFMA matmuls.
// State = 16x16 complex matrix (orientation alternates per pass).
// Per layer: pass L: X = (P_hi * H) * S   (2 mfma_f32_16x16x32_f16, re/im K-stacked)
//            pass R: Y = L * X^T          (2 mfma)
// CNOT(3..6) perms folded into LDS write addressing; CNOT(0..2) into H's rows.
// Single 2048B state buffer per wave (same-wave DS ops are in-order), XOR-swizzled
// 16B granules (phys_g = logical_g ^ (line&7)) -> b128 reads at minimum 8 phases.
// p-buffer: 16 elems * 512B, swizzled by element&7 (write key e&7 == read key n&7).
// Measurement: 8 sign-matrix MFMAs over the 16-element p batch.

typedef _Float16 half8  __attribute__((ext_vector_type(8)));
typedef _Float16 half2v __attribute__((ext_vector_type(2)));
typedef float    float4v __attribute__((ext_vector_type(4)));
typedef unsigned int uint2v __attribute__((ext_vector_type(2)));

#define PBASE 2048
#define WAVE_LDS 10240   // 2048 state + 8192 p; 4 waves * 10240 = 40960B -> 4 blocks/CU

#define MEMFENCE() __asm__ volatile("" ::: "memory")

__device__ __forceinline__ unsigned pk(float a, float b) {
  half2v v = { (_Float16)a, (_Float16)b };   // RNE conversions
  return __builtin_bit_cast(unsigned, v);
}

// ---------------- setup: build A-fragments (gates + signs) into d_ws ----------------
// 4 waves: wave t builds layer t's 4 fragments; wave 0 also builds 8 sign fragments.
// Fragment f (24 total), lane-sliced: ws_half8[f*64 + lane]. A-layout: A[m=lane&15][k=quad*8+j].
__global__ void qsetup(const float* __restrict__ w, _Float16* __restrict__ wsf) {
  const int tid = threadIdx.x;
  const int lane = tid & 63, t = tid >> 6;
  const int quad = lane >> 4, m = lane & 15;
  half8* F = (half8*)wsf;
  // pi_hi(m) = sigma0(sigma1(sigma2(m))): row perm for CNOTs 0,1,2 (folded into H rows)
  int mr = m ^ ((m >> 1) & 1);
  mr ^= ((mr >> 2) & 1) << 1;
  mr ^= ((mr >> 3) & 1) << 2;
  float gr[8][2][2], gi[8][2][2];
  for (int qq = 0; qq < 8; ++qq) {
    float th = w[(t * 8 + qq) * 2 + 0];
    float tz = w[(t * 8 + qq) * 2 + 1];
    float c, s, zc, zs;
    __sincosf(0.5f * th, &s, &c);
    __sincosf(0.5f * tz, &zs, &zc);
    // g = diag(e^{-i tz/2}, e^{+i tz/2}) * RY(th)
    gr[qq][0][0] =  zc * c; gi[qq][0][0] = -zs * c;
    gr[qq][0][1] = -zc * s; gi[qq][0][1] =  zs * s;
    gr[qq][1][0] =  zc * s; gi[qq][1][0] =  zs * s;
    gr[qq][1][1] =  zc * c; gi[qq][1][1] =  zs * c;
  }
  half8 aR, aI, bR, bI;
  for (int j = 0; j < 8; ++j) {
    const int col = quad * 4 + (j >> 1), comp = j & 1;
    // H~[m][col] = H[pi_hi(m)][col], H = kron(g0,g1,g2,g3)
    float hr = 1.f, hi = 0.f;
    for (int qq = 0; qq < 4; ++qq) {
      int rb = (mr >> (3 - qq)) & 1, cb = (col >> (3 - qq)) & 1;
      float ar = gr[qq][rb][cb], ai = gi[qq][rb][cb];
      float nr = hr * ar - hi * ai, ni = hr * ai + hi * ar;
      hr = nr; hi = ni;
    }
    aR[j] = comp ? (_Float16)(-hi) : (_Float16)hr;  // A_R = [G_r, -G_i] interleaved
    aI[j] = comp ? (_Float16)(hr)  : (_Float16)hi;  // A_I = [G_i,  G_r]
    // L[m][col] = kron(g4,g5,g6,g7)
    float wr = 1.f, wi = 0.f;
    for (int qq = 4; qq < 8; ++qq) {
      int rb = (m >> (7 - qq)) & 1, cb = (col >> (7 - qq)) & 1;
      float ar = gr[qq][rb][cb], ai = gi[qq][rb][cb];
      float nr = wr * ar - wi * ai, ni = wr * ai + wi * ar;
      wr = nr; wi = ni;
    }
    bR[j] = comp ? (_Float16)(-wi) : (_Float16)wr;
    bI[j] = comp ? (_Float16)(wr)  : (_Float16)wi;
  }
  F[(t * 4 + 0) * 64 + lane] = aR;
  F[(t * 4 + 1) * 64 + lane] = aI;
  F[(t * 4 + 2) * 64 + lane] = bR;
  F[(t * 4 + 3) * 64 + lane] = bI;
  if (t == 0) {
    // Sign fragments: A[m=qubit][k = state slot s = u*16 + l'], slot perm absorbed.
    for (int c = 0; c < 8; ++c) {
      half8 sg;
      for (int j = 0; j < 8; ++j) {
        int s_ = c * 32 + quad * 8 + j;
        int u = s_ >> 4, lp = s_ & 15;
        int y = lp ^ ((u & 1) << 3);
        y ^= ((y >> 3) & 1) << 2;  // sigma4
        y ^= ((y >> 2) & 1) << 1;  // sigma5
        y ^= (y >> 1) & 1;         // sigma6
        float sv = 0.f;
        if (m < 8) {
          int bit = (m < 4) ? ((u >> (3 - m)) & 1) : ((y >> (7 - m)) & 1);
          sv = bit ? -1.f : 1.f;
        }
        sg[j] = (_Float16)sv;
      }
      F[(16 + c) * 64 + lane] = sg;
    }
  }
}

// ---------------- main kernel: 1024 blocks * 4 waves, 16 elements per wave ----------------
__launch_bounds__(256)
__global__ void qmain(const float* __restrict__ x, const _Float16* __restrict__ wsf,
                      float* __restrict__ out) {
  __shared__ __align__(16) unsigned char smem[4 * WAVE_LDS];
  const int tid = threadIdx.x;
  const int lane = tid & 63, wv = tid >> 6;
  const int quad = lane >> 4, n = lane & 15;
  unsigned char* sm = smem + wv * WAVE_LDS;
  const half8* F = (const half8*)wsf;

  half8 aLR[4], aLI[4], aRR[4], aRI[4];
#pragma unroll
  for (int t = 0; t < 4; ++t) {
    aLR[t] = F[(t * 4 + 0) * 64 + lane];
    aLI[t] = F[(t * 4 + 1) * 64 + lane];
    aRR[t] = F[(t * 4 + 2) * 64 + lane];
    aRI[t] = F[(t * 4 + 3) * 64 + lane];
  }

  // Per-wave-constant LDS byte offsets. State buffer: line L (16 lines x 128B),
  // logical 16B-granule g stored at phys granule g ^ (L&7).
  unsigned wS[4], wP[4];
#pragma unroll
  for (int r = 0; r < 4; ++r) {
    int L = quad * 4 + r;                         // pass-L out: line = row u
    wS[r] = (unsigned)(L * 128 + (((n >> 2) ^ (L & 7)) << 4) + (n & 3) * 4);
    int lp = quad * 4 + r;                        // pass-R out: permuted line
    int y = lp ^ ((n & 1) << 3);                  // C3: control u bit0 (=n&1), target l bit3
    y ^= ((y >> 3) & 1) << 2;                     // sigma456^{-1}
    y ^= ((y >> 2) & 1) << 1;
    y ^= (y >> 1) & 1;
    wP[r] = (unsigned)(y * 128 + (((n >> 2) ^ (y & 7)) << 4) + (n & 3) * 4);
  }
  // B-frag read (both passes): line n, logical granule quad
  const unsigned rS = (unsigned)(n * 128 + ((quad ^ (n & 7)) << 4));
  // p-write: element e, logical granule 2n + (quad>>1), dword (quad&1)*2
  const unsigned pWg = (unsigned)(2 * n + (quad >> 1));
  const unsigned pWlo = (unsigned)(PBASE + (quad & 1) * 8);

  const int group = blockIdx.x * 4 + wv;  // 4096 groups of 16 elements
  const int e0 = group * 16;
  const float4v zz = {0.f, 0.f, 0.f, 0.f};

  for (int e = 0; e < 16; ++e) {
    // ---- encoding: product state, B-fragment for layer-0 pass L built in registers ----
    const float* xe = x + (size_t)(e0 + e) * 8;
    float xv = (lane < 8) ? xe[lane] : 0.f;
    float cc = __cosf(0.5f * xv), ss = __sinf(0.5f * xv);
    float cq[8], sq[8];
#pragma unroll
    for (int q = 0; q < 8; ++q) { cq[q] = __shfl(cc, q, 64); sq[q] = __shfl(ss, q, 64); }
    float f0 = (quad & 2) ? sq[0] : cq[0];
    float f1 = (quad & 1) ? sq[1] : cq[1];
    float f4 = (n & 8) ? sq[4] : cq[4];
    float f5 = (n & 4) ? sq[5] : cq[5];
    float f6 = (n & 2) ? sq[6] : cq[6];
    float f7 = (n & 1) ? sq[7] : cq[7];
    float pb = f0 * f1 * f4 * f5 * f6 * f7;
    float v0 = pb * cq[2] * cq[3], v1 = pb * cq[2] * sq[3];
    float v2 = pb * sq[2] * cq[3], v3 = pb * sq[2] * sq[3];
    half8 bf;
    bf[0] = (_Float16)v0; bf[1] = (_Float16)0.f;
    bf[2] = (_Float16)v1; bf[3] = (_Float16)0.f;
    bf[4] = (_Float16)v2; bf[5] = (_Float16)0.f;
    bf[6] = (_Float16)v3; bf[7] = (_Float16)0.f;

#pragma unroll
    for (int t = 0; t < 4; ++t) {
      // ---- pass L: X = H~ * S ----
      half8 bL;
      if (t == 0) { bL = bf; }
      else { MEMFENCE(); bL = *(const half8*)(sm + rS); }
      float4v xr = __builtin_amdgcn_mfma_f32_16x16x32_f16(aLR[t], bL, zz, 0, 0, 0);
      float4v xi = __builtin_amdgcn_mfma_f32_16x16x32_f16(aLI[t], bL, zz, 0, 0, 0);
      MEMFENCE();
      *(unsigned*)(sm + wS[0]) = pk(xr[0], xi[0]);
      *(unsigned*)(sm + wS[1]) = pk(xr[1], xi[1]);
      *(unsigned*)(sm + wS[2]) = pk(xr[2], xi[2]);
      *(unsigned*)(sm + wS[3]) = pk(xr[3], xi[3]);
      // ---- pass R: Y = L * X^T ----
      MEMFENCE();
      half8 bRf = *(const half8*)(sm + rS);
      float4v yr = __builtin_amdgcn_mfma_f32_16x16x32_f16(aRR[t], bRf, zz, 0, 0, 0);
      float4v yi = __builtin_amdgcn_mfma_f32_16x16x32_f16(aRI[t], bRf, zz, 0, 0, 0);
      MEMFENCE();
      if (t < 3) {
        *(unsigned*)(sm + wP[0]) = pk(yr[0], yi[0]);
        *(unsigned*)(sm + wP[1]) = pk(yr[1], yi[1]);
        *(unsigned*)(sm + wP[2]) = pk(yr[2], yi[2]);
        *(unsigned*)(sm + wP[3]) = pk(yr[3], yi[3]);
      } else {
        float p0 = yr[0] * yr[0] + yi[0] * yi[0];
        float p1 = yr[1] * yr[1] + yi[1] * yi[1];
        float p2 = yr[2] * yr[2] + yi[2] * yi[2];
        float p3 = yr[3] * yr[3] + yi[3] * yi[3];
        uint2v pv = { pk(p0, p1), pk(p2, p3) };
        unsigned pOff = pWlo + (unsigned)e * 512u + ((pWg ^ (unsigned)(e & 7)) << 4);
        *(uint2v*)(sm + pOff) = pv;
      }
    }
  }

  // ---- measurement: exps(16 elems x 8 qubits) = Sign(16x256) * P(256x16), 8 MFMAs ----
  half8 sf[8];
#pragma unroll
  for (int c = 0; c < 8; ++c) sf[c] = F[(16 + c) * 64 + lane];
  float4v acc = {0.f, 0.f, 0.f, 0.f};
  MEMFENCE();
#pragma unroll
  for (int c = 0; c < 8; ++c) {
    unsigned pR = (unsigned)(PBASE + n * 512 + ((((unsigned)(c * 4 + quad)) ^ (unsigned)(n & 7)) << 4));
    half8 pbv = *(const half8*)(sm + pR);
    acc = __builtin_amdgcn_mfma_f32_16x16x32_f16(sf[c], pbv, acc, 0, 0, 0);
  }
  // C layout: col = lane&15 = element, row = quad*4+reg = qubit (rows 8-15 are zero)
  if (quad < 2) {
    float4v* o = (float4v*)(out + (size_t)(e0 + n) * 8 + quad * 4);
    *o = acc;
  }
}

extern "C" void kernel_launch(void* const* d_in, const int* in_sizes, int n_in,
                              void* d_out, int out_size, void* d_ws, size_t ws_size,
                              hipStream_t stream) {
  const float* x = (const float*)d_in[0];
  const float* w = (const float*)d_in[1];
  float* out = (float*)d_out;
  _Float16* fr = (_Float16*)d_ws;  // 24 fragments * 64 lanes * 16 B = 24576 B
  qsetup<<<dim3(1), dim3(256), 0, stream>>>(w, fr);
  qmain<<<dim3(1024), dim3(256), 0, stream>>>(x, fr, out);
}

// Round 3
// 95.230 us; speedup vs baseline: 1.1825x; 1.0133x over previous
//
#include <hip/hip_runtime.h>

// QuantumLayer: 8-qubit, 4-layer VQC via complex 16x16 MFMA matmuls. Single kernel.
// State = 16x16 complex matrix; per layer pass L (2 mfma) + pass R (2 mfma),
// CNOT perms folded into LDS write addressing / gate rows. ILP2: two element
// chains per wave in disjoint 2KB swizzled state buffers. Gate fragments built
// cooperatively (wave t -> layer t) in LDS once, then held in VGPRs
// (launch_bounds(256,2) -> 256-VGPR budget; round-2's VGPR=60 showed the
// compiler was re-fetching fragments from global inside the hot loop).

typedef _Float16 half8  __attribute__((ext_vector_type(8)));
typedef float    float4v __attribute__((ext_vector_type(4)));
typedef unsigned int uint2v __attribute__((ext_vector_type(2)));

#define PBASE 4096
#define WAVE_LDS 12288   // 2x2048 state (ILP2) + 8192 p; block = 49152

#define MEMFENCE() __asm__ volatile("" ::: "memory")

__device__ __forceinline__ unsigned pk2(float a, float b) {
  auto v = __builtin_amdgcn_cvt_pkrtz(a, b);   // v_cvt_pkrtz_f16_f32, 1 instr
  return __builtin_bit_cast(unsigned, v);
}
__device__ __forceinline__ float rdlane(float v, int l) {
  return __builtin_bit_cast(float, __builtin_amdgcn_readlane(__builtin_bit_cast(int, v), l));
}

__launch_bounds__(256, 2)
__global__ void qmain(const float* __restrict__ x, const float* __restrict__ w,
                      float* __restrict__ out) {
  __shared__ __align__(16) unsigned char smem[4 * WAVE_LDS];
  const int tid = threadIdx.x;
  const int lane = tid & 63, wv = tid >> 6;
  const int quad = lane >> 4, n = lane & 15;
  unsigned char* sm = smem + wv * WAVE_LDS;

  // ---- phase 0: wave wv builds layer wv's 4 gate fragments into block LDS ----
  {
    const int t = wv;
    int mr = n ^ ((n >> 1) & 1);          // pi_hi: CNOTs 0,1,2 folded into H rows
    mr ^= ((mr >> 2) & 1) << 1;
    mr ^= ((mr >> 3) & 1) << 2;
    float gr[8][2][2], gi[8][2][2];
    for (int qq = 0; qq < 8; ++qq) {
      float th = w[(t * 8 + qq) * 2 + 0];
      float tz = w[(t * 8 + qq) * 2 + 1];
      float c, s, zc, zs;
      __sincosf(0.5f * th, &s, &c);
      __sincosf(0.5f * tz, &zs, &zc);
      gr[qq][0][0] =  zc * c; gi[qq][0][0] = -zs * c;
      gr[qq][0][1] = -zc * s; gi[qq][0][1] =  zs * s;
      gr[qq][1][0] =  zc * s; gi[qq][1][0] =  zs * s;
      gr[qq][1][1] =  zc * c; gi[qq][1][1] =  zs * c;
    }
    half8 aR, aI, bR, bI;
    for (int j = 0; j < 8; ++j) {
      const int col = quad * 4 + (j >> 1), comp = j & 1;
      float hr = 1.f, hi = 0.f;                       // H~ = kron(g0..g3), perm rows
      for (int qq = 0; qq < 4; ++qq) {
        int rb = (mr >> (3 - qq)) & 1, cb = (col >> (3 - qq)) & 1;
        float ar = gr[qq][rb][cb], ai = gi[qq][rb][cb];
        float nr = hr * ar - hi * ai, ni = hr * ai + hi * ar;
        hr = nr; hi = ni;
      }
      aR[j] = comp ? (_Float16)(-hi) : (_Float16)hr;  // A_R = [G_r, -G_i] K-interleaved
      aI[j] = comp ? (_Float16)(hr)  : (_Float16)hi;  // A_I = [G_i,  G_r]
      float wr = 1.f, wi = 0.f;                       // L = kron(g4..g7)
      for (int qq = 4; qq < 8; ++qq) {
        int rb = (n >> (7 - qq)) & 1, cb = (col >> (7 - qq)) & 1;
        float ar = gr[qq][rb][cb], ai = gi[qq][rb][cb];
        float nr = wr * ar - wi * ai, ni = wr * ai + wi * ar;
        wr = nr; wi = ni;
      }
      bR[j] = comp ? (_Float16)(-wi) : (_Float16)wr;
      bI[j] = comp ? (_Float16)(wr)  : (_Float16)wi;
    }
    half8* FB = (half8*)smem;
    FB[(t * 4 + 0) * 64 + lane] = aR;
    FB[(t * 4 + 1) * 64 + lane] = aI;
    FB[(t * 4 + 2) * 64 + lane] = bR;
    FB[(t * 4 + 3) * 64 + lane] = bI;
  }
  __syncthreads();
  half8 aLR[4], aLI[4], aRR[4], aRI[4];
#pragma unroll
  for (int t = 0; t < 4; ++t) {
    const half8* FB = (const half8*)smem;
    aLR[t] = FB[(t * 4 + 0) * 64 + lane];
    aLI[t] = FB[(t * 4 + 1) * 64 + lane];
    aRR[t] = FB[(t * 4 + 2) * 64 + lane];
    aRI[t] = FB[(t * 4 + 3) * 64 + lane];
  }
  __syncthreads();  // work areas may now overwrite the fragment staging region

  // ---- sign fragments (weight-independent): per-lane bit math, no LDS ----
  half8 sf[8];
#pragma unroll
  for (int c = 0; c < 8; ++c) {
#pragma unroll
    for (int j = 0; j < 8; ++j) {
      int u = 2 * c + (quad >> 1);
      int lp = (quad & 1) * 8 + j;
      int y = lp ^ ((u & 1) << 3);
      y ^= ((y >> 3) & 1) << 2;
      y ^= ((y >> 2) & 1) << 1;
      y ^= (y >> 1) & 1;
      float sv = 0.f;
      if (n < 8) {
        int bit = (n < 4) ? ((u >> (3 - n)) & 1) : ((y >> (7 - n)) & 1);
        sv = bit ? -1.f : 1.f;
      }
      sf[c][j] = (_Float16)sv;
    }
  }

  // ---- per-wave-constant LDS byte offsets (relative to a 2KB chain buffer) ----
  unsigned wS[4], wP[4];
#pragma unroll
  for (int r = 0; r < 4; ++r) {
    int L = quad * 4 + r;                          // pass-L out: line = row u
    wS[r] = (unsigned)(L * 128 + (((n >> 2) ^ (L & 7)) << 4) + (n & 3) * 4);
    int y = L ^ ((n & 1) << 3);                    // pass-R out: CNOT-permuted line
    y ^= ((y >> 3) & 1) << 2;
    y ^= ((y >> 2) & 1) << 1;
    y ^= (y >> 1) & 1;
    wP[r] = (unsigned)(y * 128 + (((n >> 2) ^ (y & 7)) << 4) + (n & 3) * 4);
  }
  const unsigned rS = (unsigned)(n * 128 + ((quad ^ (n & 7)) << 4));
  const unsigned pWg = (unsigned)(2 * n + (quad >> 1));
  const unsigned pWlo = (unsigned)(PBASE + (quad & 1) * 8);

  unsigned char* smA = sm;
  unsigned char* smB = sm + 2048;
  const int e0 = (blockIdx.x * 4 + wv) * 32;
  const float4v zz = {0.f, 0.f, 0.f, 0.f};

  for (int g = 0; g < 2; ++g) {
    const int base = e0 + g * 16;
    // prefetch all 16 elements' angles; sincos once per lane
    float xa = x[(size_t)base * 8 + lane];
    float xb = x[(size_t)base * 8 + 64 + lane];
    float ca, sa, cb, sb;
    __sincosf(0.5f * xa, &sa, &ca);
    __sincosf(0.5f * xb, &sb, &cb);

    for (int i = 0; i < 8; ++i) {   // ILP2 pairs: elements (2i, 2i+1)
      half8 bv[2];
#pragma unroll
      for (int h = 0; h < 2; ++h) {
        const int e = 2 * i + h;
        const float cs = (i < 4) ? ca : cb;   // uniform select, then readlane
        const float sn = (i < 4) ? sa : sb;
        const int lb = (e & 7) * 8;
        float cq[8], sq[8];
#pragma unroll
        for (int q = 0; q < 8; ++q) {
          cq[q] = rdlane(cs, lb + q);
          sq[q] = rdlane(sn, lb + q);
        }
        float f0 = (quad & 2) ? sq[0] : cq[0];
        float f1 = (quad & 1) ? sq[1] : cq[1];
        float f4 = (n & 8) ? sq[4] : cq[4];
        float f5 = (n & 4) ? sq[5] : cq[5];
        float f6 = (n & 2) ? sq[6] : cq[6];
        float f7 = (n & 1) ? sq[7] : cq[7];
        float pb = f0 * f1 * f4 * f5 * f6 * f7;
        float v0 = pb * cq[2] * cq[3], v1 = pb * cq[2] * sq[3];
        float v2 = pb * sq[2] * cq[3], v3 = pb * sq[2] * sq[3];
        union { unsigned u[4]; half8 v; } bb;
        bb.u[0] = pk2(v0, 0.f); bb.u[1] = pk2(v1, 0.f);
        bb.u[2] = pk2(v2, 0.f); bb.u[3] = pk2(v3, 0.f);
        bv[h] = bb.v;
      }

      half8 bA = bv[0], bB = bv[1];
      const unsigned eA = (unsigned)(2 * i), eB = eA + 1u;
      const unsigned pA = pWlo + eA * 512u + ((pWg ^ (eA & 7u)) << 4);
      const unsigned pB = pWlo + eB * 512u + ((pWg ^ (eB & 7u)) << 4);
#pragma unroll
      for (int t = 0; t < 4; ++t) {
        if (t) {
          MEMFENCE();
          bA = *(const half8*)(smA + rS);
          bB = *(const half8*)(smB + rS);
        }
        float4v xrA = __builtin_amdgcn_mfma_f32_16x16x32_f16(aLR[t], bA, zz, 0, 0, 0);
        float4v xiA = __builtin_amdgcn_mfma_f32_16x16x32_f16(aLI[t], bA, zz, 0, 0, 0);
        float4v xrB = __builtin_amdgcn_mfma_f32_16x16x32_f16(aLR[t], bB, zz, 0, 0, 0);
        float4v xiB = __builtin_amdgcn_mfma_f32_16x16x32_f16(aLI[t], bB, zz, 0, 0, 0);
        MEMFENCE();
#pragma unroll
        for (int r = 0; r < 4; ++r) {
          *(unsigned*)(smA + wS[r]) = pk2(xrA[r], xiA[r]);
          *(unsigned*)(smB + wS[r]) = pk2(xrB[r], xiB[r]);
        }
        MEMFENCE();
        half8 cA = *(const half8*)(smA + rS);
        half8 cB = *(const half8*)(smB + rS);
        float4v yrA = __builtin_amdgcn_mfma_f32_16x16x32_f16(aRR[t], cA, zz, 0, 0, 0);
        float4v yiA = __builtin_amdgcn_mfma_f32_16x16x32_f16(aRI[t], cA, zz, 0, 0, 0);
        float4v yrB = __builtin_amdgcn_mfma_f32_16x16x32_f16(aRR[t], cB, zz, 0, 0, 0);
        float4v yiB = __builtin_amdgcn_mfma_f32_16x16x32_f16(aRI[t], cB, zz, 0, 0, 0);
        MEMFENCE();
        if (t < 3) {
#pragma unroll
          for (int r = 0; r < 4; ++r) {
            *(unsigned*)(smA + wP[r]) = pk2(yrA[r], yiA[r]);
            *(unsigned*)(smB + wP[r]) = pk2(yrB[r], yiB[r]);
          }
        } else {
          float a0 = yrA[0] * yrA[0] + yiA[0] * yiA[0];
          float a1 = yrA[1] * yrA[1] + yiA[1] * yiA[1];
          float a2 = yrA[2] * yrA[2] + yiA[2] * yiA[2];
          float a3 = yrA[3] * yrA[3] + yiA[3] * yiA[3];
          uint2v pvA = { pk2(a0, a1), pk2(a2, a3) };
          *(uint2v*)(sm + pA) = pvA;
          float b0 = yrB[0] * yrB[0] + yiB[0] * yiB[0];
          float b1 = yrB[1] * yrB[1] + yiB[1] * yiB[1];
          float b2 = yrB[2] * yrB[2] + yiB[2] * yiB[2];
          float b3 = yrB[3] * yrB[3] + yiB[3] * yiB[3];
          uint2v pvB = { pk2(b0, b1), pk2(b2, b3) };
          *(uint2v*)(sm + pB) = pvB;
        }
      }
    }

    // ---- measurement: exps(16 elems x 8 qubits) = Sign(16x256) * P(256x16) ----
    float4v acc = zz;
    MEMFENCE();
#pragma unroll
    for (int c = 0; c < 8; ++c) {
      unsigned pR = (unsigned)(PBASE + n * 512 +
                               ((((unsigned)(c * 4 + quad)) ^ (unsigned)(n & 7)) << 4));
      half8 pbv = *(const half8*)(sm + pR);
      acc = __builtin_amdgcn_mfma_f32_16x16x32_f16(sf[c], pbv, acc, 0, 0, 0);
    }
    MEMFENCE();
    // C layout: col = n = element, row = quad*4+reg = qubit (rows 8-15 zero)
    if (quad < 2) {
      float4v* o = (float4v*)(out + (size_t)(base + n) * 8 + quad * 4);
      *o = acc;
    }
  }
}

extern "C" void kernel_launch(void* const* d_in, const int* in_sizes, int n_in,
                              void* d_out, int out_size, void* d_ws, size_t ws_size,
                              hipStream_t stream) {
  const float* x = (const float*)d_in[0];
  const float* w = (const float*)d_in[1];
  float* out = (float*)d_out;
  qmain<<<dim3(512), dim3(256), 0, stream>>>(x, w, out);
}

// Round 4
// 84.355 us; speedup vs baseline: 1.3349x; 1.1289x over previous
//
#include <hip/hip_runtime.h>

// QuantumLayer: 8-qubit, 4-layer VQC via complex 16x16 MFMA matmuls. Single kernel.
// Per layer: pass L (2 mfma, re/im K-stacked) + pass R (2 mfma); CNOT perms folded
// into LDS write addressing / gate rows. ILP2: two element chains per wave in
// disjoint 2KB swizzled state buffers.
// ROUND-4 FIX: round 3's setup phase used runtime-indexed arrays (gr[qq][rb][cb],
// half8 inserts in a rolled loop) -> scratch demotion -> 33 MB HBM scratch traffic
// (WRITE_SIZE 2->34.8 MB) and fragment spills (VGPR=84 < 96 needed). This version
// has ZERO dynamic indexing: gate = phase(rb)*ry[rb][cb] with ry real -> pure
// cndmask selects; all loops unrolled; sign fragments recomputed at measurement.

typedef _Float16 half8  __attribute__((ext_vector_type(8)));
typedef float    float4v __attribute__((ext_vector_type(4)));
typedef unsigned int uint2v __attribute__((ext_vector_type(2)));

#define PBASE 4096
#define WAVE_LDS 12288   // 2x2048 state (ILP2) + 8192 p; block = 49152

#define MEMFENCE() __asm__ volatile("" ::: "memory")

__device__ __forceinline__ unsigned pk2(float a, float b) {
  auto v = __builtin_amdgcn_cvt_pkrtz(a, b);   // v_cvt_pkrtz_f16_f32, 1 instr
  return __builtin_bit_cast(unsigned, v);
}
__device__ __forceinline__ float rdlane(float v, int l) {
  return __builtin_bit_cast(float, __builtin_amdgcn_readlane(__builtin_bit_cast(int, v), l));
}

__launch_bounds__(256, 2)
__global__ void qmain(const float* __restrict__ x, const float* __restrict__ w,
                      float* __restrict__ out) {
  __shared__ __align__(16) unsigned char smem[4 * WAVE_LDS];
  const int tid = threadIdx.x;
  const int lane = tid & 63, wv = tid >> 6;
  const int quad = lane >> 4, n = lane & 15;
  unsigned char* sm = smem + wv * WAVE_LDS;

  // ---- phase 0: wave wv builds layer wv's 4 gate fragments into block LDS ----
  {
    const int t = wv;
    int mr = n ^ ((n >> 1) & 1);          // pi_hi: CNOTs 0,1,2 folded into H rows
    mr ^= ((mr >> 2) & 1) << 1;
    mr ^= ((mr >> 3) & 1) << 2;
    float cS[8], sS[8], zcS[8], zsS[8];
#pragma unroll
    for (int qq = 0; qq < 8; ++qq) {
      float th = w[(t * 8 + qq) * 2 + 0];
      float tz = w[(t * 8 + qq) * 2 + 1];
      __sincosf(0.5f * th, &sS[qq], &cS[qq]);
      __sincosf(0.5f * tz, &zsS[qq], &zcS[qq]);
    }
    union { _Float16 h[8]; half8 v; } aR, aI, bR, bI;
#pragma unroll
    for (int ci = 0; ci < 4; ++ci) {
      const int col = quad * 4 + ci;
      // H~[mr][col], H = kron(g0..g3); g[rb][cb] = (zc, rb?zs:-zs) * ry, ry real:
      // ry[rb][cb] = (rb==cb) ? c : (rb ? s : -s)
      float hr = 1.f, hi = 0.f;
#pragma unroll
      for (int qq = 0; qq < 4; ++qq) {
        int rb = (mr >> (3 - qq)) & 1, cb = (col >> (3 - qq)) & 1;
        float ryv = (rb == cb) ? cS[qq] : (rb ? sS[qq] : -sS[qq]);
        float ar = zcS[qq] * ryv;
        float ai = (rb ? zsS[qq] : -zsS[qq]) * ryv;
        float nr = hr * ar - hi * ai, ni = hr * ai + hi * ar;
        hr = nr; hi = ni;
      }
      aR.h[2 * ci + 0] = (_Float16)hr;   // A_R = [G_r, -G_i] K-interleaved
      aR.h[2 * ci + 1] = (_Float16)(-hi);
      aI.h[2 * ci + 0] = (_Float16)hi;   // A_I = [G_i,  G_r]
      aI.h[2 * ci + 1] = (_Float16)hr;
      // L[n][col], L = kron(g4..g7)
      float wr = 1.f, wi = 0.f;
#pragma unroll
      for (int qq = 0; qq < 4; ++qq) {
        int rb = (n >> (3 - qq)) & 1, cb = (col >> (3 - qq)) & 1;
        float ryv = (rb == cb) ? cS[qq + 4] : (rb ? sS[qq + 4] : -sS[qq + 4]);
        float ar = zcS[qq + 4] * ryv;
        float ai = (rb ? zsS[qq + 4] : -zsS[qq + 4]) * ryv;
        float nr = wr * ar - wi * ai, ni = wr * ai + wi * ar;
        wr = nr; wi = ni;
      }
      bR.h[2 * ci + 0] = (_Float16)wr;
      bR.h[2 * ci + 1] = (_Float16)(-wi);
      bI.h[2 * ci + 0] = (_Float16)wi;
      bI.h[2 * ci + 1] = (_Float16)wr;
    }
    half8* FB = (half8*)smem;
    FB[(t * 4 + 0) * 64 + lane] = aR.v;
    FB[(t * 4 + 1) * 64 + lane] = aI.v;
    FB[(t * 4 + 2) * 64 + lane] = bR.v;
    FB[(t * 4 + 3) * 64 + lane] = bI.v;
  }
  __syncthreads();
  half8 aLR[4], aLI[4], aRR[4], aRI[4];
#pragma unroll
  for (int t = 0; t < 4; ++t) {
    const half8* FB = (const half8*)smem;
    aLR[t] = FB[(t * 4 + 0) * 64 + lane];
    aLI[t] = FB[(t * 4 + 1) * 64 + lane];
    aRR[t] = FB[(t * 4 + 2) * 64 + lane];
    aRI[t] = FB[(t * 4 + 3) * 64 + lane];
  }
  __syncthreads();  // work areas may now overwrite the fragment staging region

  // ---- per-wave-constant LDS byte offsets (relative to a 2KB chain buffer) ----
  unsigned wS[4], wP[4];
#pragma unroll
  for (int r = 0; r < 4; ++r) {
    int L = quad * 4 + r;                          // pass-L out: line = row u
    wS[r] = (unsigned)(L * 128 + (((n >> 2) ^ (L & 7)) << 4) + (n & 3) * 4);
    int y = L ^ ((n & 1) << 3);                    // pass-R out: CNOT-permuted line
    y ^= ((y >> 3) & 1) << 2;
    y ^= ((y >> 2) & 1) << 1;
    y ^= (y >> 1) & 1;
    wP[r] = (unsigned)(y * 128 + (((n >> 2) ^ (y & 7)) << 4) + (n & 3) * 4);
  }
  const unsigned rS = (unsigned)(n * 128 + ((quad ^ (n & 7)) << 4));
  const unsigned pWg = (unsigned)(2 * n + (quad >> 1));
  const unsigned pWlo = (unsigned)(PBASE + (quad & 1) * 8);

  unsigned char* smA = sm;
  unsigned char* smB = sm + 2048;
  const int e0 = (blockIdx.x * 4 + wv) * 32;
  const float4v zz = {0.f, 0.f, 0.f, 0.f};

  for (int g = 0; g < 2; ++g) {
    const int base = e0 + g * 16;
    // all 16 elements' angles; sincos once per lane
    float xa = x[(size_t)base * 8 + lane];
    float xb = x[(size_t)base * 8 + 64 + lane];
    float ca, sa, cb, sb;
    __sincosf(0.5f * xa, &sa, &ca);
    __sincosf(0.5f * xb, &sb, &cb);

    for (int i = 0; i < 8; ++i) {   // ILP2 pairs: elements (2i, 2i+1)
      half8 bv[2];
#pragma unroll
      for (int h = 0; h < 2; ++h) {
        const int e = 2 * i + h;
        const float cs = (i < 4) ? ca : cb;   // uniform select, then readlane
        const float sn = (i < 4) ? sa : sb;
        const int lb = (e & 7) * 8;
        float cq[8], sq[8];
#pragma unroll
        for (int q = 0; q < 8; ++q) {
          cq[q] = rdlane(cs, lb + q);
          sq[q] = rdlane(sn, lb + q);
        }
        float f0 = (quad & 2) ? sq[0] : cq[0];
        float f1 = (quad & 1) ? sq[1] : cq[1];
        float f4 = (n & 8) ? sq[4] : cq[4];
        float f5 = (n & 4) ? sq[5] : cq[5];
        float f6 = (n & 2) ? sq[6] : cq[6];
        float f7 = (n & 1) ? sq[7] : cq[7];
        float pb = f0 * f1 * f4 * f5 * f6 * f7;
        float v0 = pb * cq[2] * cq[3], v1 = pb * cq[2] * sq[3];
        float v2 = pb * sq[2] * cq[3], v3 = pb * sq[2] * sq[3];
        union { unsigned u[4]; half8 v; } bb;
        bb.u[0] = pk2(v0, 0.f); bb.u[1] = pk2(v1, 0.f);
        bb.u[2] = pk2(v2, 0.f); bb.u[3] = pk2(v3, 0.f);
        bv[h] = bb.v;
      }

      half8 bA = bv[0], bB = bv[1];
      const unsigned eA = (unsigned)(2 * i), eB = eA + 1u;
      const unsigned pA = pWlo + eA * 512u + ((pWg ^ (eA & 7u)) << 4);
      const unsigned pB = pWlo + eB * 512u + ((pWg ^ (eB & 7u)) << 4);
#pragma unroll
      for (int t = 0; t < 4; ++t) {
        if (t) {
          MEMFENCE();
          bA = *(const half8*)(smA + rS);
          bB = *(const half8*)(smB + rS);
        }
        float4v xrA = __builtin_amdgcn_mfma_f32_16x16x32_f16(aLR[t], bA, zz, 0, 0, 0);
        float4v xiA = __builtin_amdgcn_mfma_f32_16x16x32_f16(aLI[t], bA, zz, 0, 0, 0);
        float4v xrB = __builtin_amdgcn_mfma_f32_16x16x32_f16(aLR[t], bB, zz, 0, 0, 0);
        float4v xiB = __builtin_amdgcn_mfma_f32_16x16x32_f16(aLI[t], bB, zz, 0, 0, 0);
        MEMFENCE();
#pragma unroll
        for (int r = 0; r < 4; ++r) {
          *(unsigned*)(smA + wS[r]) = pk2(xrA[r], xiA[r]);
          *(unsigned*)(smB + wS[r]) = pk2(xrB[r], xiB[r]);
        }
        MEMFENCE();
        half8 cA = *(const half8*)(smA + rS);
        half8 cB = *(const half8*)(smB + rS);
        float4v yrA = __builtin_amdgcn_mfma_f32_16x16x32_f16(aRR[t], cA, zz, 0, 0, 0);
        float4v yiA = __builtin_amdgcn_mfma_f32_16x16x32_f16(aRI[t], cA, zz, 0, 0, 0);
        float4v yrB = __builtin_amdgcn_mfma_f32_16x16x32_f16(aRR[t], cB, zz, 0, 0, 0);
        float4v yiB = __builtin_amdgcn_mfma_f32_16x16x32_f16(aRI[t], cB, zz, 0, 0, 0);
        MEMFENCE();
        if (t < 3) {
#pragma unroll
          for (int r = 0; r < 4; ++r) {
            *(unsigned*)(smA + wP[r]) = pk2(yrA[r], yiA[r]);
            *(unsigned*)(smB + wP[r]) = pk2(yrB[r], yiB[r]);
          }
        } else {
          float a0 = yrA[0] * yrA[0] + yiA[0] * yiA[0];
          float a1 = yrA[1] * yrA[1] + yiA[1] * yiA[1];
          float a2 = yrA[2] * yrA[2] + yiA[2] * yiA[2];
          float a3 = yrA[3] * yrA[3] + yiA[3] * yiA[3];
          uint2v pvA = { pk2(a0, a1), pk2(a2, a3) };
          *(uint2v*)(sm + pA) = pvA;
          float b0 = yrB[0] * yrB[0] + yiB[0] * yiB[0];
          float b1 = yrB[1] * yrB[1] + yiB[1] * yiB[1];
          float b2 = yrB[2] * yrB[2] + yiB[2] * yiB[2];
          float b3 = yrB[3] * yrB[3] + yiB[3] * yiB[3];
          uint2v pvB = { pk2(b0, b1), pk2(b2, b3) };
          *(uint2v*)(sm + pB) = pvB;
        }
      }
    }

    // ---- measurement: exps(16 elems x 8 qubits) = Sign(16x256) * P(256x16) ----
    // Sign fragments recomputed inline (pure bit math) to keep them out of the
    // long-lived register set.
    float4v acc = zz;
    MEMFENCE();
#pragma unroll
    for (int c = 0; c < 8; ++c) {
      union { _Float16 h[8]; half8 v; } sg;
#pragma unroll
      for (int j = 0; j < 8; ++j) {
        int u = 2 * c + (quad >> 1);
        int lp = (quad & 1) * 8 + j;
        int y = lp ^ ((u & 1) << 3);
        y ^= ((y >> 3) & 1) << 2;
        y ^= ((y >> 2) & 1) << 1;
        y ^= (y >> 1) & 1;
        float sv = 0.f;
        if (n < 8) {
          int bit = (n < 4) ? ((u >> (3 - n)) & 1) : ((y >> (7 - n)) & 1);
          sv = bit ? -1.f : 1.f;
        }
        sg.h[j] = (_Float16)sv;
      }
      unsigned pR = (unsigned)(PBASE + n * 512 +
                               ((((unsigned)(c * 4 + quad)) ^ (unsigned)(n & 7)) << 4));
      half8 pbv = *(const half8*)(sm + pR);
      acc = __builtin_amdgcn_mfma_f32_16x16x32_f16(sg.v, pbv, acc, 0, 0, 0);
    }
    MEMFENCE();
    // C layout: col = n = element, row = quad*4+reg = qubit (rows 8-15 zero)
    if (quad < 2) {
      float4v* o = (float4v*)(out + (size_t)(base + n) * 8 + quad * 4);
      *o = acc;
    }
  }
}

extern "C" void kernel_launch(void* const* d_in, const int* in_sizes, int n_in,
                              void* d_out, int out_size, void* d_ws, size_t ws_size,
                              hipStream_t stream) {
  const float* x = (const float*)d_in[0];
  const float* w = (const float*)d_in[1];
  float* out = (float*)d_out;
  qmain<<<dim3(512), dim3(256), 0, stream>>>(x, w, out);
}

// Round 5
// 79.489 us; speedup vs baseline: 1.4166x; 1.0612x over previous
//
#include <hip/hip_runtime.h>

// QuantumLayer: 8-qubit, 4-layer VQC. ROUND-5: zero LDS for state evolution.
// Key identity: with STATE as the MFMA A-operand and GATE as B, the C-layout
// output of each pass is exactly the A-fragment of the next pass (the
// transpose is absorbed by alternating the passive dimension u,l,u,l...).
//   pass L: D1 = S^T * G_L   (G_L[2c+comp][u'] from H~[u'][c], H~ rows P^-1-folded)
//   pass R: D2 = X  * G_R    (G_R[2p+comp][l''] from L~[l''][tau(p)])
// CNOTs 0-2 -> P folded into H~; CNOTs 3-6 -> sigma(l,u)=tau(l)^15*(u&1):
// tau (linear) baked into G_R k-order + encoding label (lane n <-> true l=tau(n));
// residual odd-u part: tau^-1(15)=8 -> swap lanes n<->n^8 for odd-u registers
// = one v_mov_dpp row_ror:8 per odd reg (VALU pipe). Only remaining LDS:
// 16-element p-buffer for the sign-matrix measurement MFMAs (conflict-free).

typedef _Float16 half8  __attribute__((ext_vector_type(8)));
typedef float    float4v __attribute__((ext_vector_type(4)));
typedef unsigned int uint2v __attribute__((ext_vector_type(2)));
typedef unsigned int uint4v __attribute__((ext_vector_type(4)));

#define MEMFENCE() __asm__ volatile("" ::: "memory")

__device__ __forceinline__ unsigned pk2(float a, float b) {
  auto v = __builtin_amdgcn_cvt_pkrtz(a, b);   // packed f32->f16x2, 1 instr
  return __builtin_bit_cast(unsigned, v);
}
__device__ __forceinline__ float rdlane(float v, int l) {
  return __builtin_bit_cast(float, __builtin_amdgcn_readlane(__builtin_bit_cast(int, v), l));
}
// lane n <- lane n^8 within each 16-lane row (row_ror:8; rotation by 8 == xor 8)
__device__ __forceinline__ unsigned sw8u(unsigned v) {
  return (unsigned)__builtin_amdgcn_mov_dpp((int)v, 0x128, 0xf, 0xf, false);
}
__device__ __forceinline__ float sw8f(float v) {
  return __builtin_bit_cast(float,
      __builtin_amdgcn_mov_dpp(__builtin_bit_cast(int, v), 0x128, 0xf, 0xf, false));
}
__device__ __forceinline__ int tauf(int l) {   // CNOTs 4,5,6 on l (linear)
  int y = l ^ (((l >> 3) & 1) << 2);
  y ^= ((y >> 2) & 1) << 1;
  y ^= (y >> 1) & 1;
  return y;
}

__launch_bounds__(256, 2)
__global__ void qmain(const float* __restrict__ x, const float* __restrict__ w,
                      float* __restrict__ out) {
  __shared__ __align__(16) unsigned char smem[32768];  // staging 16K (overlaid), 4x8K p
  const int tid = threadIdx.x;
  const int lane = tid & 63, wv = tid >> 6;
  const int quad = lane >> 4, n = lane & 15;

  // ---- phase 0: wave wv builds layer wv's 4 gate B-frags into staging LDS ----
  {
    const int t = wv;
    int mr = n ^ ((n >> 1) & 1);            // P^-1(n): CNOTs 0,1,2 fold (col = u')
    mr ^= ((mr >> 2) & 1) << 1;
    mr ^= ((mr >> 3) & 1) << 2;
    float cS[8], sS[8], zcS[8], zsS[8];
#pragma unroll
    for (int qq = 0; qq < 8; ++qq) {
      float th = w[(t * 8 + qq) * 2 + 0];
      float tz = w[(t * 8 + qq) * 2 + 1];
      __sincosf(0.5f * th, &sS[qq], &cS[qq]);
      __sincosf(0.5f * tz, &zsS[qq], &zcS[qq]);
    }
    union { _Float16 h[8]; half8 v; } bLR, bLI, bRR, bRI;
#pragma unroll
    for (int ci = 0; ci < 4; ++ci) {
      const int kp = quad * 4 + ci;          // k-pair index
      // G_L value h = H~[n][kp] = H[mr][kp];  g = diag(e^{-i tz/2},e^{+i tz/2})*RY
      float hr = 1.f, hi = 0.f;
#pragma unroll
      for (int j = 0; j < 4; ++j) {
        int rb = (mr >> (3 - j)) & 1, cb = (kp >> (3 - j)) & 1;
        float ryv = (rb == cb) ? cS[j] : (rb ? sS[j] : -sS[j]);
        float ar = zcS[j] * ryv;
        float ai = (rb ? zsS[j] : -zsS[j]) * ryv;
        float nr = hr * ar - hi * ai, ni = hr * ai + hi * ar;
        hr = nr; hi = ni;
      }
      bLR.h[2 * ci] = (_Float16)hr;  bLR.h[2 * ci + 1] = (_Float16)(-hi);
      bLI.h[2 * ci] = (_Float16)hi;  bLI.h[2 * ci + 1] = (_Float16)hr;
      // G_R value v = L~[n][tau(kp)]  (tau bakes the deferred column relabel)
      int yk = tauf(kp);
      float wr = 1.f, wi = 0.f;
#pragma unroll
      for (int j = 0; j < 4; ++j) {          // qubits 4+j
        int rb = (n >> (3 - j)) & 1, cb = (yk >> (3 - j)) & 1;
        float ryv = (rb == cb) ? cS[4 + j] : (rb ? sS[4 + j] : -sS[4 + j]);
        float ar = zcS[4 + j] * ryv;
        float ai = (rb ? zsS[4 + j] : -zsS[4 + j]) * ryv;
        float nr = wr * ar - wi * ai, ni = wr * ai + wi * ar;
        wr = nr; wi = ni;
      }
      bRR.h[2 * ci] = (_Float16)wr;  bRR.h[2 * ci + 1] = (_Float16)(-wi);
      bRI.h[2 * ci] = (_Float16)wi;  bRI.h[2 * ci + 1] = (_Float16)wr;
    }
    half8* FB = (half8*)smem;
    FB[(t * 4 + 0) * 64 + lane] = bLR.v;
    FB[(t * 4 + 1) * 64 + lane] = bLI.v;
    FB[(t * 4 + 2) * 64 + lane] = bRR.v;
    FB[(t * 4 + 3) * 64 + lane] = bRI.v;
  }
  __syncthreads();
  half8 BLR[4], BLI[4], BRR[4], BRI[4];
#pragma unroll
  for (int t = 0; t < 4; ++t) {
    const half8* FB = (const half8*)smem;
    BLR[t] = FB[(t * 4 + 0) * 64 + lane];
    BLI[t] = FB[(t * 4 + 1) * 64 + lane];
    BRR[t] = FB[(t * 4 + 2) * 64 + lane];
    BRI[t] = FB[(t * 4 + 3) * 64 + lane];
  }
  __syncthreads();   // p-buffers may now overlay the staging region

  // ---- sign fragments: A[m=qubit][k=slot s=c*32+quad*8+jj]; slot wrote
  // p[u = s&15][true l = tau(s>>4)]; rows 8-15 zero ----
  half8 sf[8];
#pragma unroll
  for (int c = 0; c < 8; ++c) {
    union { _Float16 h[8]; half8 v; } sg;
#pragma unroll
    for (int jj = 0; jj < 8; ++jj) {
      int u = (quad & 1) * 8 + jj;
      int y = tauf(2 * c + (quad >> 1));
      float sv = 0.f;
      if (n < 8) {
        int bit = (n < 4) ? ((u >> (3 - n)) & 1) : ((y >> (7 - n)) & 1);
        sv = bit ? -1.f : 1.f;
      }
      sg.h[jj] = (_Float16)sv;
    }
    sf[c] = sg.v;
  }

  unsigned char* smp = smem + wv * 8192;
  const unsigned pWg = (unsigned)(2 * n + (quad >> 1));   // p-write granule
  const unsigned pWlo = (unsigned)((quad & 1) * 8);
  const int e0 = (blockIdx.x * 4 + wv) * 32;
  const float4v zz = {0.f, 0.f, 0.f, 0.f};
  const int ytau = tauf(n);     // lane's true l label

  for (int g = 0; g < 2; ++g) {
    const int base = e0 + g * 16;
    float xa = x[(size_t)base * 8 + lane];
    float xb = x[(size_t)base * 8 + 64 + lane];
    float ca, sa, cb, sb;
    __sincosf(0.5f * xa, &sa, &ca);
    __sincosf(0.5f * xb, &sb, &cb);

    for (int i = 0; i < 8; ++i) {   // ILP2: elements (2i, 2i+1)
      uint4v st[2];
#pragma unroll
      for (int h = 0; h < 2; ++h) {
        const int e = 2 * i + h;
        const float cs = (i < 4) ? ca : cb;
        const float sn = (i < 4) ? sa : sb;
        const int lb = (e & 7) * 8;
        float cq[8], sq[8];
#pragma unroll
        for (int q = 0; q < 8; ++q) { cq[q] = rdlane(cs, lb + q); sq[q] = rdlane(sn, lb + q); }
        float f0 = (quad & 2) ? sq[0] : cq[0];
        float f1 = (quad & 1) ? sq[1] : cq[1];
        float f4 = (ytau & 8) ? sq[4] : cq[4];
        float f5 = (ytau & 4) ? sq[5] : cq[5];
        float f6 = (ytau & 2) ? sq[6] : cq[6];
        float f7 = (ytau & 1) ? sq[7] : cq[7];
        float pb = f0 * f1 * f4 * f5 * f6 * f7;
        st[h][0] = pk2(pb * cq[2] * cq[3], 0.f);
        st[h][1] = pk2(pb * cq[2] * sq[3], 0.f);
        st[h][2] = pk2(pb * sq[2] * cq[3], 0.f);
        st[h][3] = pk2(pb * sq[2] * sq[3], 0.f);
      }

#pragma unroll
      for (int t = 0; t < 4; ++t) {
        half8 A0 = __builtin_bit_cast(half8, st[0]);
        half8 A1 = __builtin_bit_cast(half8, st[1]);
        // pass L: D1 = S^T * G_L  -> lane holds X[n][tau-pos 4q+r]
        float4v xr0 = __builtin_amdgcn_mfma_f32_16x16x32_f16(A0, BLR[t], zz, 0, 0, 0);
        float4v xi0 = __builtin_amdgcn_mfma_f32_16x16x32_f16(A0, BLI[t], zz, 0, 0, 0);
        float4v xr1 = __builtin_amdgcn_mfma_f32_16x16x32_f16(A1, BLR[t], zz, 0, 0, 0);
        float4v xi1 = __builtin_amdgcn_mfma_f32_16x16x32_f16(A1, BLI[t], zz, 0, 0, 0);
        uint4v X0 = { pk2(xr0[0], xi0[0]), pk2(xr0[1], xi0[1]),
                      pk2(xr0[2], xi0[2]), pk2(xr0[3], xi0[3]) };
        uint4v X1 = { pk2(xr1[0], xi1[0]), pk2(xr1[1], xi1[1]),
                      pk2(xr1[2], xi1[2]), pk2(xr1[3], xi1[3]) };
        half8 XA0 = __builtin_bit_cast(half8, X0);
        half8 XA1 = __builtin_bit_cast(half8, X1);
        // pass R: D2 = X * G_R  -> lane holds S''[u=4q+r][l''=n]
        float4v yr0 = __builtin_amdgcn_mfma_f32_16x16x32_f16(XA0, BRR[t], zz, 0, 0, 0);
        float4v yi0 = __builtin_amdgcn_mfma_f32_16x16x32_f16(XA0, BRI[t], zz, 0, 0, 0);
        float4v yr1 = __builtin_amdgcn_mfma_f32_16x16x32_f16(XA1, BRR[t], zz, 0, 0, 0);
        float4v yi1 = __builtin_amdgcn_mfma_f32_16x16x32_f16(XA1, BRI[t], zz, 0, 0, 0);
        if (t < 3) {
          // CNOT fix: odd-u registers swap lanes n<->n^8; tau deferred to gates
          st[0][0] = pk2(yr0[0], yi0[0]);
          st[0][1] = sw8u(pk2(yr0[1], yi0[1]));
          st[0][2] = pk2(yr0[2], yi0[2]);
          st[0][3] = sw8u(pk2(yr0[3], yi0[3]));
          st[1][0] = pk2(yr1[0], yi1[0]);
          st[1][1] = sw8u(pk2(yr1[1], yi1[1]));
          st[1][2] = pk2(yr1[2], yi1[2]);
          st[1][3] = sw8u(pk2(yr1[3], yi1[3]));
        } else {
          // final CNOT on f32, then p = |amp|^2 -> LDS p-buffer
          float r01 = sw8f(yr0[1]), i01 = sw8f(yi0[1]);
          float r03 = sw8f(yr0[3]), i03 = sw8f(yi0[3]);
          float p00 = yr0[0] * yr0[0] + yi0[0] * yi0[0];
          float p01 = r01 * r01 + i01 * i01;
          float p02 = yr0[2] * yr0[2] + yi0[2] * yi0[2];
          float p03 = r03 * r03 + i03 * i03;
          float r11 = sw8f(yr1[1]), i11 = sw8f(yi1[1]);
          float r13 = sw8f(yr1[3]), i13 = sw8f(yi1[3]);
          float p10 = yr1[0] * yr1[0] + yi1[0] * yi1[0];
          float p11 = r11 * r11 + i11 * i11;
          float p12 = yr1[2] * yr1[2] + yi1[2] * yi1[2];
          float p13 = r13 * r13 + i13 * i13;
          const unsigned eA = (unsigned)(2 * i), eB = eA + 1u;
          unsigned pA = eA * 512u + ((pWg ^ (eA & 7u)) << 4) + pWlo;
          unsigned pB = eB * 512u + ((pWg ^ (eB & 7u)) << 4) + pWlo;
          MEMFENCE();
          uint2v v0 = { pk2(p00, p01), pk2(p02, p03) };
          *(uint2v*)(smp + pA) = v0;
          uint2v v1 = { pk2(p10, p11), pk2(p12, p13) };
          *(uint2v*)(smp + pB) = v1;
          MEMFENCE();
        }
      }
    }

    // ---- measurement: exps(16 elems x 8 qubits) = Sign(16x256) * P(256x16) ----
    float4v acc = zz;
    MEMFENCE();
#pragma unroll
    for (int c = 0; c < 8; ++c) {
      unsigned pR = (unsigned)(n * 512 +
                               ((((unsigned)(c * 4 + quad)) ^ (unsigned)(n & 7)) << 4));
      half8 pbv = *(const half8*)(smp + pR);
      acc = __builtin_amdgcn_mfma_f32_16x16x32_f16(sf[c], pbv, acc, 0, 0, 0);
    }
    MEMFENCE();
    // C layout: col = n = element, row = quad*4+reg = qubit (rows 8-15 zero)
    if (quad < 2) {
      float4v* o = (float4v*)(out + (size_t)(base + n) * 8 + quad * 4);
      *o = acc;
    }
  }
}

extern "C" void kernel_launch(void* const* d_in, const int* in_sizes, int n_in,
                              void* d_out, int out_size, void* d_ws, size_t ws_size,
                              hipStream_t stream) {
  const float* x = (const float*)d_in[0];
  const float* w = (const float*)d_in[1];
  float* out = (float*)d_out;
  qmain<<<dim3(512), dim3(256), 0, stream>>>(x, w, out);
}

// Round 6
// 75.715 us; speedup vs baseline: 1.4872x; 1.0498x over previous
//
#include <hip/hip_runtime.h>

// QuantumLayer: 8-qubit, 4-layer VQC, state evolution entirely in registers.
// With STATE as MFMA A-operand and GATE as B, each pass's C-layout output is
// exactly the next pass's A-fragment (transpose absorbed by alternating the
// passive dimension u,l,u,l...). CNOTs 0-2 folded into H~ rows; CNOTs 4-6 (tau,
// linear) baked into G_R k-order + encoding lane labels; CNOT3 residual = lane
// swap n<->n^8 on odd-u registers = v_mov_dpp row_ror:8 (VALU pipe). LDS only
// for the 16-element p-buffer feeding the sign-matrix measurement MFMAs.
// ROUND-6: r5 was latency-bound (2 waves/SIMD, 2 chains/wave, serial
// MFMA->pack->MFMA core ~90cyc x8/elem; measured ~31us vs ~8us issue model).
// Fix: ILP4 (4 chains/wave -> 16 independent MFMAs in flight per phase), full
// unroll (readlane imm indices), hoisted x-loads/sincos. Occupancy stays 2
// blocks/CU (raising it would cross the 128-VGPR cliff; frags need ~96 regs).

typedef _Float16 half8  __attribute__((ext_vector_type(8)));
typedef float    float4v __attribute__((ext_vector_type(4)));
typedef unsigned int uint2v __attribute__((ext_vector_type(2)));
typedef unsigned int uint4v __attribute__((ext_vector_type(4)));

#define MEMFENCE() __asm__ volatile("" ::: "memory")

__device__ __forceinline__ unsigned pk2(float a, float b) {
  auto v = __builtin_amdgcn_cvt_pkrtz(a, b);   // packed f32->f16x2, 1 instr
  return __builtin_bit_cast(unsigned, v);
}
__device__ __forceinline__ float rdlane(float v, int l) {
  return __builtin_bit_cast(float, __builtin_amdgcn_readlane(__builtin_bit_cast(int, v), l));
}
// lane n <- lane n^8 within each 16-lane row (row_ror:8)
__device__ __forceinline__ unsigned sw8u(unsigned v) {
  return (unsigned)__builtin_amdgcn_mov_dpp((int)v, 0x128, 0xf, 0xf, false);
}
__device__ __forceinline__ float sw8f(float v) {
  return __builtin_bit_cast(float,
      __builtin_amdgcn_mov_dpp(__builtin_bit_cast(int, v), 0x128, 0xf, 0xf, false));
}
__device__ __forceinline__ int tauf(int l) {   // CNOTs 4,5,6 on l (linear)
  int y = l ^ (((l >> 3) & 1) << 2);
  y ^= ((y >> 2) & 1) << 1;
  y ^= (y >> 1) & 1;
  return y;
}

__launch_bounds__(256, 2)
__global__ void qmain(const float* __restrict__ x, const float* __restrict__ w,
                      float* __restrict__ out) {
  __shared__ __align__(16) unsigned char smem[32768];  // staging 16K (overlaid), 4x8K p
  const int tid = threadIdx.x;
  const int lane = tid & 63, wv = tid >> 6;
  const int quad = lane >> 4, n = lane & 15;

  // ---- phase 0: wave wv builds layer wv's 4 gate B-frags into staging LDS ----
  {
    const int t = wv;
    int mr = n ^ ((n >> 1) & 1);            // P^-1(n): CNOTs 0,1,2 fold
    mr ^= ((mr >> 2) & 1) << 1;
    mr ^= ((mr >> 3) & 1) << 2;
    float cS[8], sS[8], zcS[8], zsS[8];
#pragma unroll
    for (int qq = 0; qq < 8; ++qq) {
      float th = w[(t * 8 + qq) * 2 + 0];
      float tz = w[(t * 8 + qq) * 2 + 1];
      __sincosf(0.5f * th, &sS[qq], &cS[qq]);
      __sincosf(0.5f * tz, &zsS[qq], &zcS[qq]);
    }
    union { _Float16 h[8]; half8 v; } bLR, bLI, bRR, bRI;
#pragma unroll
    for (int ci = 0; ci < 4; ++ci) {
      const int kp = quad * 4 + ci;          // k-pair index
      float hr = 1.f, hi = 0.f;              // G_L = H~[n][kp] = H[mr][kp]
#pragma unroll
      for (int j = 0; j < 4; ++j) {
        int rb = (mr >> (3 - j)) & 1, cb = (kp >> (3 - j)) & 1;
        float ryv = (rb == cb) ? cS[j] : (rb ? sS[j] : -sS[j]);
        float ar = zcS[j] * ryv;
        float ai = (rb ? zsS[j] : -zsS[j]) * ryv;
        float nr = hr * ar - hi * ai, ni = hr * ai + hi * ar;
        hr = nr; hi = ni;
      }
      bLR.h[2 * ci] = (_Float16)hr;  bLR.h[2 * ci + 1] = (_Float16)(-hi);
      bLI.h[2 * ci] = (_Float16)hi;  bLI.h[2 * ci + 1] = (_Float16)hr;
      int yk = tauf(kp);                     // G_R = L~[n][tau(kp)]
      float wr = 1.f, wi = 0.f;
#pragma unroll
      for (int j = 0; j < 4; ++j) {
        int rb = (n >> (3 - j)) & 1, cb = (yk >> (3 - j)) & 1;
        float ryv = (rb == cb) ? cS[4 + j] : (rb ? sS[4 + j] : -sS[4 + j]);
        float ar = zcS[4 + j] * ryv;
        float ai = (rb ? zsS[4 + j] : -zsS[4 + j]) * ryv;
        float nr = wr * ar - wi * ai, ni = wr * ai + wi * ar;
        wr = nr; wi = ni;
      }
      bRR.h[2 * ci] = (_Float16)wr;  bRR.h[2 * ci + 1] = (_Float16)(-wi);
      bRI.h[2 * ci] = (_Float16)wi;  bRI.h[2 * ci + 1] = (_Float16)wr;
    }
    half8* FB = (half8*)smem;
    FB[(t * 4 + 0) * 64 + lane] = bLR.v;
    FB[(t * 4 + 1) * 64 + lane] = bLI.v;
    FB[(t * 4 + 2) * 64 + lane] = bRR.v;
    FB[(t * 4 + 3) * 64 + lane] = bRI.v;
  }
  __syncthreads();
  half8 BLR[4], BLI[4], BRR[4], BRI[4];
#pragma unroll
  for (int t = 0; t < 4; ++t) {
    const half8* FB = (const half8*)smem;
    BLR[t] = FB[(t * 4 + 0) * 64 + lane];
    BLI[t] = FB[(t * 4 + 1) * 64 + lane];
    BRR[t] = FB[(t * 4 + 2) * 64 + lane];
    BRI[t] = FB[(t * 4 + 3) * 64 + lane];
  }
  __syncthreads();   // p-buffers may now overlay the staging region

  // ---- sign fragments (resident): A[m=qubit][k=slot]; rows 8-15 zero ----
  half8 sf[8];
#pragma unroll
  for (int c = 0; c < 8; ++c) {
    union { _Float16 h[8]; half8 v; } sg;
#pragma unroll
    for (int jj = 0; jj < 8; ++jj) {
      int u = (quad & 1) * 8 + jj;
      int y = tauf(2 * c + (quad >> 1));
      float sv = 0.f;
      if (n < 8) {
        int bit = (n < 4) ? ((u >> (3 - n)) & 1) : ((y >> (7 - n)) & 1);
        sv = bit ? -1.f : 1.f;
      }
      sg.h[jj] = (_Float16)sv;
    }
    sf[c] = sg.v;
  }

  unsigned char* smp = smem + wv * 8192;
  const unsigned pWg = (unsigned)(2 * n + (quad >> 1));   // p-write granule
  const unsigned pWlo = (unsigned)((quad & 1) * 8);
  const int e0 = (blockIdx.x * 4 + wv) * 32;
  const float4v zz = {0.f, 0.f, 0.f, 0.f};
  const int ytau = tauf(n);     // lane's true l label

  // hoisted angle loads + sincos for all 32 elements
  const float* xp = x + (size_t)e0 * 8;
  float x0 = xp[lane], x1 = xp[64 + lane], x2 = xp[128 + lane], x3 = xp[192 + lane];
  float c0, s0, c1, s1, c2, s2, c3, s3;
  __sincosf(0.5f * x0, &s0, &c0);
  __sincosf(0.5f * x1, &s1, &c1);
  __sincosf(0.5f * x2, &s2, &c2);
  __sincosf(0.5f * x3, &s3, &c3);

  for (int g = 0; g < 2; ++g) {
    const int base = e0 + g * 16;
    const float CA = g ? c2 : c0, SA = g ? s2 : s0;   // elements 0-7 of group
    const float CB = g ? c3 : c1, SB = g ? s3 : s1;   // elements 8-15

#pragma unroll
    for (int i = 0; i < 4; ++i) {   // ILP4: elements e = 4i+h, h=0..3
      uint4v st[4];
#pragma unroll
      for (int h = 0; h < 4; ++h) {
        const int e = 4 * i + h;
        const float cs = (e < 8) ? CA : CB;    // compile-time select
        const float sn = (e < 8) ? SA : SB;
        const int lb = (e & 7) * 8;            // constant readlane index
        float cq[8], sq[8];
#pragma unroll
        for (int q = 0; q < 8; ++q) { cq[q] = rdlane(cs, lb + q); sq[q] = rdlane(sn, lb + q); }
        float f0 = (quad & 2) ? sq[0] : cq[0];
        float f1 = (quad & 1) ? sq[1] : cq[1];
        float f4 = (ytau & 8) ? sq[4] : cq[4];
        float f5 = (ytau & 4) ? sq[5] : cq[5];
        float f6 = (ytau & 2) ? sq[6] : cq[6];
        float f7 = (ytau & 1) ? sq[7] : cq[7];
        float pb = f0 * f1 * f4 * f5 * f6 * f7;
        st[h][0] = pk2(pb * cq[2] * cq[3], 0.f);
        st[h][1] = pk2(pb * cq[2] * sq[3], 0.f);
        st[h][2] = pk2(pb * sq[2] * cq[3], 0.f);
        st[h][3] = pk2(pb * sq[2] * sq[3], 0.f);
      }

#pragma unroll
      for (int t = 0; t < 4; ++t) {
        // pass L: D1 = S^T * G_L  (16 independent MFMAs across 4 chains)
        float4v xr[4], xi[4];
#pragma unroll
        for (int c = 0; c < 4; ++c) {
          half8 A = __builtin_bit_cast(half8, st[c]);
          xr[c] = __builtin_amdgcn_mfma_f32_16x16x32_f16(A, BLR[t], zz, 0, 0, 0);
          xi[c] = __builtin_amdgcn_mfma_f32_16x16x32_f16(A, BLI[t], zz, 0, 0, 0);
        }
        uint4v X[4];
#pragma unroll
        for (int c = 0; c < 4; ++c) {
          X[c][0] = pk2(xr[c][0], xi[c][0]);
          X[c][1] = pk2(xr[c][1], xi[c][1]);
          X[c][2] = pk2(xr[c][2], xi[c][2]);
          X[c][3] = pk2(xr[c][3], xi[c][3]);
        }
        // pass R: D2 = X * G_R
        float4v yr[4], yi[4];
#pragma unroll
        for (int c = 0; c < 4; ++c) {
          half8 XA = __builtin_bit_cast(half8, X[c]);
          yr[c] = __builtin_amdgcn_mfma_f32_16x16x32_f16(XA, BRR[t], zz, 0, 0, 0);
          yi[c] = __builtin_amdgcn_mfma_f32_16x16x32_f16(XA, BRI[t], zz, 0, 0, 0);
        }
        if (t < 3) {
          // CNOT fix: odd-u regs swap lanes n<->n^8 (tau deferred to gates)
#pragma unroll
          for (int c = 0; c < 4; ++c) {
            st[c][0] = pk2(yr[c][0], yi[c][0]);
            st[c][1] = sw8u(pk2(yr[c][1], yi[c][1]));
            st[c][2] = pk2(yr[c][2], yi[c][2]);
            st[c][3] = sw8u(pk2(yr[c][3], yi[c][3]));
          }
        } else {
          // final CNOT on f32, p = |amp|^2 -> LDS p-buffer
          MEMFENCE();
#pragma unroll
          for (int c = 0; c < 4; ++c) {
            float r1 = sw8f(yr[c][1]), i1 = sw8f(yi[c][1]);
            float r3 = sw8f(yr[c][3]), i3 = sw8f(yi[c][3]);
            float p0 = yr[c][0] * yr[c][0] + yi[c][0] * yi[c][0];
            float p1 = r1 * r1 + i1 * i1;
            float p2 = yr[c][2] * yr[c][2] + yi[c][2] * yi[c][2];
            float p3 = r3 * r3 + i3 * i3;
            const unsigned e = (unsigned)(4 * i + c);
            unsigned pOff = e * 512u + ((pWg ^ (e & 7u)) << 4) + pWlo;
            uint2v v = { pk2(p0, p1), pk2(p2, p3) };
            *(uint2v*)(smp + pOff) = v;
          }
          MEMFENCE();
        }
      }
    }

    // ---- measurement: exps(16 elems x 8 qubits) = Sign(16x256) * P(256x16) ----
    float4v acc = zz;
    MEMFENCE();
#pragma unroll
    for (int c = 0; c < 8; ++c) {
      unsigned pR = (unsigned)(n * 512 +
                               ((((unsigned)(c * 4 + quad)) ^ (unsigned)(n & 7)) << 4));
      half8 pbv = *(const half8*)(smp + pR);
      acc = __builtin_amdgcn_mfma_f32_16x16x32_f16(sf[c], pbv, acc, 0, 0, 0);
    }
    MEMFENCE();
    // C layout: col = n = element, row = quad*4+reg = qubit (rows 8-15 zero)
    if (quad < 2) {
      float4v* o = (float4v*)(out + (size_t)(base + n) * 8 + quad * 4);
      *o = acc;
    }
  }
}

extern "C" void kernel_launch(void* const* d_in, const int* in_sizes, int n_in,
                              void* d_out, int out_size, void* d_ws, size_t ws_size,
                              hipStream_t stream) {
  const float* x = (const float*)d_in[0];
  const float* w = (const float*)d_in[1];
  float* out = (float*)d_out;
  qmain<<<dim3(512), dim3(256), 0, stream>>>(x, w, out);
}